// Round 1
// baseline (150.951 us; speedup 1.0000x reference)
//
#include <hip/hip_runtime.h>
#include <hip/hip_bf16.h>

// spatial_attention: out = weights @ (H W1^T) + (H W2^T + b)
//   K0: pack GbT[c][k] = G[k][c] bf16, where G[k][c<256]=W[c][k], G[k][c>=256]=W[c-256][k+256]
//   K1: P = H @ G (MFMA bf16): P1T[b][d][j] (transposed, bf16), P2[b][j][d] = ..+bias (bf16)
//   K2: per (b, 128-row tile): weight numerators -> LDS, MFMA vs P1T[b], row-scale, +P2, store
// Workspace: GbT 256KB @0 ; P1T 32MB @1MB ; P2 32MB @33MB  (needs ~65MB of d_ws)

typedef __attribute__((ext_vector_type(4))) float  f32x4;
typedef __attribute__((ext_vector_type(8))) short  bf16x8;
typedef __attribute__((ext_vector_type(4))) short  bf16x4;

#define EPSC 1e-14f

__device__ __forceinline__ short f2bf(float v) {
  __hip_bfloat16 h = __float2bfloat16(v);
  return *reinterpret_cast<short*>(&h);
}
__device__ __forceinline__ float bf2f(unsigned short u) {
  union { unsigned int i; float f; } c; c.i = ((unsigned int)u) << 16; return c.f;
}

// ---------------- K0 ----------------
__global__ void k0_pack(const float* __restrict__ W, short* __restrict__ GbT) {
  int idx = blockIdx.x * 256 + threadIdx.x;   // 512 blocks x 256 thr = 131072
  int c = idx >> 8, k = idx & 255;
  float v = (c < 256) ? W[c * 512 + k] : W[(c - 256) * 512 + 256 + k];
  GbT[c * 256 + k] = f2bf(v);
}

// ---------------- K1: grid 1024 (64 H-rows each), block 512 ----------------
// out tile: 64 n-rows x 512 c-cols.  8 waves: wn=wid>>2 (2 x 32 rows), wc=wid&3 (4 x 128 cols)
__global__ __launch_bounds__(512) void k1_proj(
    const float* __restrict__ H, const short* __restrict__ GbT,
    const float* __restrict__ bias,
    short* __restrict__ P1T, short* __restrict__ P2) {
  extern __shared__ char sm[];
  char* sA = sm;                       // [64][528]B : 64 n x 256 k bf16, +16B pad
  char* sB = sm + 33792;               // [512][144]B: 512 c x 64 k bf16, +16B pad
  float* sBias = (float*)(sm + 33792 + 73728);
  const int t = threadIdx.x;
  const int n0 = blockIdx.x * 64;
  const int b  = n0 >> 8;
  const int jb = n0 & 255;

  // stage A (H rows, fp32 -> bf16)
  #pragma unroll
  for (int p = 0; p < 8; ++p) {
    int q = t + 512 * p;               // 0..4095 : n = q>>6, float4 col = q&63
    int n = q >> 6, c4 = q & 63;
    f32x4 hv = *(const f32x4*)(H + (size_t)(n0 + n) * 256 + c4 * 4);
    bf16x4 pk;
    pk[0] = f2bf(hv[0]); pk[1] = f2bf(hv[1]); pk[2] = f2bf(hv[2]); pk[3] = f2bf(hv[3]);
    *(bf16x4*)(sA + n * 528 + c4 * 8) = pk;
  }
  if (t < 256) sBias[t] = bias[t];

  const int wid = t >> 6, l = t & 63;
  const int wn = wid >> 2, wc = wid & 3;
  const int lr = l & 15, lg = l >> 4;
  f32x4 acc[2][8] = {};

  for (int kk = 0; kk < 256; kk += 64) {
    __syncthreads();                   // prev chunk consumed (and A-stage visible at kk=0)
    #pragma unroll
    for (int p = 0; p < 8; ++p) {
      int z = t + 512 * p;             // 0..4095 : c = z>>3, 16B slot = z&7
      int c = z >> 3, s = z & 7;
      bf16x8 v = *(const bf16x8*)(GbT + (size_t)c * 256 + kk + s * 8);
      *(bf16x8*)(sB + c * 144 + s * 16) = v;
    }
    __syncthreads();
    #pragma unroll
    for (int sub = 0; sub < 2; ++sub) {
      bf16x8 a[2], bb[8];
      #pragma unroll
      for (int m = 0; m < 2; ++m) {
        int row = wn * 32 + m * 16 + lr;
        a[m] = *(const bf16x8*)(sA + row * 528 + (kk + sub * 32 + lg * 8) * 2);
      }
      #pragma unroll
      for (int f = 0; f < 8; ++f) {
        int c = wc * 128 + f * 16 + lr;
        bb[f] = *(const bf16x8*)(sB + c * 144 + sub * 64 + lg * 16);
      }
      #pragma unroll
      for (int m = 0; m < 2; ++m) {
        #pragma unroll
        for (int f = 0; f < 8; ++f)
          acc[m][f] = __builtin_amdgcn_mfma_f32_16x16x32_bf16(a[m], bb[f], acc[m][f], 0, 0, 0);
      }
    }
  }

  // epilogue: D row=(lg*4+r) -> n, col=lr -> c
  #pragma unroll
  for (int m = 0; m < 2; ++m) {
    int nl = wn * 32 + m * 16 + lg * 4;
    #pragma unroll
    for (int f = 0; f < 8; ++f) {
      int c = wc * 128 + f * 16 + lr;
      f32x4 v = acc[m][f];
      if (c < 256) {                   // P1T[b][c][j] : 4 consecutive j -> 8B store
        bf16x4 pk;
        pk[0] = f2bf(v[0]); pk[1] = f2bf(v[1]); pk[2] = f2bf(v[2]); pk[3] = f2bf(v[3]);
        *(bf16x4*)(P1T + (size_t)b * 65536 + (size_t)c * 256 + jb + nl) = pk;
      } else {                         // P2[b][j][d] + bias
        int d = c - 256;
        float bs = sBias[d];
        #pragma unroll
        for (int r = 0; r < 4; ++r)
          P2[(size_t)b * 65536 + (size_t)(jb + nl + r) * 256 + d] = f2bf(v[r] + bs);
      }
    }
  }
}

// ---------------- K2: grid 512 (b = blk>>1, 128-row half = blk&1), block 512 ----------------
// LDS: we[128][528]=67584 ; sB[256][144]=36864 ; dom 20736 ; mask 1024 ; scale 512 -> 126720B
__global__ __launch_bounds__(512) void k2_attn(
    const float* __restrict__ dist, const float* __restrict__ bear,
    const float* __restrict__ head, const float* __restrict__ seqmask,
    const float* __restrict__ domain, const short* __restrict__ P1T,
    const short* __restrict__ P2, float* __restrict__ out) {
  extern __shared__ char sm[];
  char*  we     = sm;                          // weight numerators, bf16, [128][264 shorts]
  char*  sB     = sm + 67584;                  // P1T chunk [256 d][64 k] bf16 padded
  float* sDom   = (float*)(sm + 104448);
  float* sMask  = (float*)(sm + 125184);
  float* sScale = (float*)(sm + 126208);
  const int t  = threadIdx.x;
  const int b  = blockIdx.x >> 1;
  const int i0 = (blockIdx.x & 1) * 128;

  for (int x = t; x < 72 * 72; x += 512) sDom[x] = domain[x];
  if (t < 256) sMask[t] = seqmask[b * 256 + t];
  __syncthreads();

  // ---- phase 1: weight numerators (exp(w)+EPS for valid, 0 otherwise); row sums ----
  {
    const int r = t >> 2, q = t & 3;           // 4 threads per row
    const int ii = i0 + r;
    const float mI = sMask[ii];
    const size_t rowbase = ((size_t)b * 256 + ii) * 256;
    float rs = 0.f;
    #pragma unroll 4
    for (int jj = 0; jj < 16; ++jj) {
      int j = q * 4 + jj * 16;
      f32x4 dv = *(const f32x4*)(dist + rowbase + j);
      f32x4 bv = *(const f32x4*)(bear + rowbase + j);
      f32x4 hv = *(const f32x4*)(head + rowbase + j);
      bf16x4 pk;
      #pragma unroll
      for (int e = 0; e < 4; ++e) {
        int je = j + e;
        int i1 = (int)fminf(fmaxf(floorf((hv[e] + 2.5f) * 0.2f), 0.f), 71.f);
        int i2 = (int)fminf(fmaxf(floorf((bv[e] + 2.5f) * 0.2f), 0.f), 71.f);
        float w = fmaxf(sDom[i1 * 72 + i2] - dv[e], 0.f);
        bool valid = (ii != je) && (mI != 0.f) && (sMask[je] != 0.f);
        float ev = 0.f;
        if (valid) {
          float ex = (w > 0.f) ? __expf(w) : 0.f;
          rs += ex;
          ev = ex + EPSC;
        }
        pk[e] = f2bf(ev);
      }
      *(bf16x4*)(we + r * 528 + j * 2) = pk;
    }
    rs += __shfl_xor(rs, 1, 64);
    rs += __shfl_xor(rs, 2, 64);
    if (q == 0) sScale[r] = 1.0f / (rs + 257.0f * EPSC);  // = 1/(sum(masked_exps)+EPS)
  }

  // ---- phase 2: out_tile = (numerators @ P1T) * rowscale + P2 ----
  const int wid = t >> 6, l = t & 63;
  const int wm = wid >> 2, wnv = wid & 3;      // wave tile 64 rows x 64 cols
  const int lr = l & 15, lg = l >> 4;
  f32x4 acc[4][4] = {};

  for (int kk = 0; kk < 256; kk += 64) {
    __syncthreads();                           // phase1 writes / prev chunk consumed
    #pragma unroll
    for (int p = 0; p < 4; ++p) {
      int z = t + 512 * p;                     // 0..2047 : d = z>>3, slot = z&7
      int d = z >> 3, s = z & 7;
      bf16x8 v = *(const bf16x8*)(P1T + (size_t)b * 65536 + (size_t)d * 256 + kk + s * 8);
      *(bf16x8*)(sB + d * 144 + s * 16) = v;
    }
    __syncthreads();
    #pragma unroll
    for (int sub = 0; sub < 2; ++sub) {
      bf16x8 a[4], bb[4];
      #pragma unroll
      for (int m = 0; m < 4; ++m) {
        int row = wm * 64 + m * 16 + lr;
        a[m] = *(const bf16x8*)(we + row * 528 + (kk + sub * 32 + lg * 8) * 2);
      }
      #pragma unroll
      for (int n = 0; n < 4; ++n) {
        int d = wnv * 64 + n * 16 + lr;
        bb[n] = *(const bf16x8*)(sB + d * 144 + sub * 64 + lg * 16);
      }
      #pragma unroll
      for (int m = 0; m < 4; ++m) {
        #pragma unroll
        for (int n = 0; n < 4; ++n)
          acc[m][n] = __builtin_amdgcn_mfma_f32_16x16x32_bf16(a[m], bb[n], acc[m][n], 0, 0, 0);
      }
    }
  }

  // epilogue
  #pragma unroll
  for (int m = 0; m < 4; ++m) {
    int rl = wm * 64 + m * 16 + lg * 4;
    #pragma unroll
    for (int n = 0; n < 4; ++n) {
      int d = wnv * 64 + n * 16 + lr;
      #pragma unroll
      for (int r = 0; r < 4; ++r) {
        int row = rl + r;
        float val = acc[m][n][r] * sScale[row]
                  + bf2f((unsigned short)P2[(size_t)b * 65536 + (size_t)(i0 + row) * 256 + d]);
        out[((size_t)b * 256 + i0 + row) * 256 + d] = val;
      }
    }
  }
}

extern "C" void kernel_launch(void* const* d_in, const int* in_sizes, int n_in,
                              void* d_out, int out_size, void* d_ws, size_t ws_size,
                              hipStream_t stream) {
  const float* hidden  = (const float*)d_in[0];
  const float* dist    = (const float*)d_in[1];
  const float* bear    = (const float*)d_in[2];
  const float* head    = (const float*)d_in[3];
  const float* seqmask = (const float*)d_in[4];
  const float* domain  = (const float*)d_in[5];
  const float* W       = (const float*)d_in[6];
  const float* bias    = (const float*)d_in[7];
  float* out = (float*)d_out;

  char* ws = (char*)d_ws;
  short* GbT = (short*)ws;                                   // 256 KB
  short* P1T = (short*)(ws + (1u << 20));                    // 32 MB
  short* P2  = (short*)(ws + (1u << 20) + (32u << 20));      // 32 MB

  k0_pack<<<512, 256, 0, stream>>>(W, GbT);
  k1_proj<<<1024, 512, 108544, stream>>>(hidden, GbT, bias, P1T, P2);
  k2_attn<<<512, 512, 126720, stream>>>(dist, bear, head, seqmask, domain, P1T, P2, out);
}

// Round 2
// 143.807 us; speedup vs baseline: 1.0497x; 1.0497x over previous
//
#include <hip/hip_runtime.h>
#include <hip/hip_bf16.h>

// spatial_attention: out = weights @ (H W1^T) + (H W2^T + b)
//   K0: pack GbT[c][k] = G[k][c] bf16
//   K1: P = H @ G (MFMA bf16): P1T[b][d][j] (transposed, bf16), P2[b][j][d] = ..+bias (bf16)
//   K2: per (b, 64-row tile): weight numerators -> LDS, MFMA vs P1T[b], row-scale, +P2, store
// Workspace: GbT 256KB @0 ; P1T 32MB @1MB ; P2 32MB @33MB

typedef __attribute__((ext_vector_type(4))) float  f32x4;
typedef __attribute__((ext_vector_type(8))) short  bf16x8;
typedef __attribute__((ext_vector_type(4))) short  bf16x4;

#define EPSC 1e-14f

__device__ __forceinline__ short f2bf(float v) {
  __hip_bfloat16 h = __float2bfloat16(v);
  return *reinterpret_cast<short*>(&h);
}
__device__ __forceinline__ float bf2f(unsigned short u) {
  union { unsigned int i; float f; } c; c.i = ((unsigned int)u) << 16; return c.f;
}

// ---------------- K0 ----------------
__global__ void k0_pack(const float* __restrict__ W, short* __restrict__ GbT) {
  int idx = blockIdx.x * 256 + threadIdx.x;
  int c = idx >> 8, k = idx & 255;
  float v = (c < 256) ? W[c * 512 + k] : W[(c - 256) * 512 + 256 + k];
  GbT[c * 256 + k] = f2bf(v);
}

// ---------------- K1: grid 1024 (64 H-rows each), block 512 ----------------
__global__ __launch_bounds__(512) void k1_proj(
    const float* __restrict__ H, const short* __restrict__ GbT,
    const float* __restrict__ bias,
    short* __restrict__ P1T, short* __restrict__ P2) {
  extern __shared__ char sm[];
  char* sA = sm;                       // [64][528]B
  char* sB = sm + 33792;               // [512][144]B
  float* sBias = (float*)(sm + 33792 + 73728);
  const int t = threadIdx.x;
  const int n0 = blockIdx.x * 64;
  const int b  = n0 >> 8;
  const int jb = n0 & 255;

  #pragma unroll
  for (int p = 0; p < 8; ++p) {
    int q = t + 512 * p;
    int n = q >> 6, c4 = q & 63;
    f32x4 hv = *(const f32x4*)(H + (size_t)(n0 + n) * 256 + c4 * 4);
    bf16x4 pk;
    pk[0] = f2bf(hv[0]); pk[1] = f2bf(hv[1]); pk[2] = f2bf(hv[2]); pk[3] = f2bf(hv[3]);
    *(bf16x4*)(sA + n * 528 + c4 * 8) = pk;
  }
  if (t < 256) sBias[t] = bias[t];

  const int wid = t >> 6, l = t & 63;
  const int wn = wid >> 2, wc = wid & 3;
  const int lr = l & 15, lg = l >> 4;
  f32x4 acc[2][8] = {};

  for (int kk = 0; kk < 256; kk += 64) {
    __syncthreads();
    #pragma unroll
    for (int p = 0; p < 8; ++p) {
      int z = t + 512 * p;
      int c = z >> 3, s = z & 7;
      bf16x8 v = *(const bf16x8*)(GbT + (size_t)c * 256 + kk + s * 8);
      *(bf16x8*)(sB + c * 144 + s * 16) = v;
    }
    __syncthreads();
    #pragma unroll
    for (int sub = 0; sub < 2; ++sub) {
      bf16x8 a[2], bb[8];
      #pragma unroll
      for (int m = 0; m < 2; ++m) {
        int row = wn * 32 + m * 16 + lr;
        a[m] = *(const bf16x8*)(sA + row * 528 + (kk + sub * 32 + lg * 8) * 2);
      }
      #pragma unroll
      for (int f = 0; f < 8; ++f) {
        int c = wc * 128 + f * 16 + lr;
        bb[f] = *(const bf16x8*)(sB + c * 144 + sub * 64 + lg * 16);
      }
      #pragma unroll
      for (int m = 0; m < 2; ++m) {
        #pragma unroll
        for (int f = 0; f < 8; ++f)
          acc[m][f] = __builtin_amdgcn_mfma_f32_16x16x32_bf16(a[m], bb[f], acc[m][f], 0, 0, 0);
      }
    }
  }

  #pragma unroll
  for (int m = 0; m < 2; ++m) {
    int nl = wn * 32 + m * 16 + lg * 4;
    #pragma unroll
    for (int f = 0; f < 8; ++f) {
      int c = wc * 128 + f * 16 + lr;
      f32x4 v = acc[m][f];
      if (c < 256) {
        bf16x4 pk;
        pk[0] = f2bf(v[0]); pk[1] = f2bf(v[1]); pk[2] = f2bf(v[2]); pk[3] = f2bf(v[3]);
        *(bf16x4*)(P1T + (size_t)b * 65536 + (size_t)c * 256 + jb + nl) = pk;
      } else {
        int d = c - 256;
        float bs = sBias[d];
        #pragma unroll
        for (int r = 0; r < 4; ++r)
          P2[(size_t)b * 65536 + (size_t)(jb + nl + r) * 256 + d] = f2bf(v[r] + bs);
      }
    }
  }
}

// ---------------- K2: grid 1024 (b = blk>>2, 64-row quarter = blk&3), block 512 ----------------
// LDS: we[64][528]=33792 ; sB[256][80]=20480 (KK=32) ; dom 20736 ; mask 1024 ; scale 256
//   -> 76288 B  => 2 blocks/CU (152KB of 160KB)
__global__ __launch_bounds__(512) void k2_attn(
    const float* __restrict__ dist, const float* __restrict__ bear,
    const float* __restrict__ head, const float* __restrict__ seqmask,
    const float* __restrict__ domain, const short* __restrict__ P1T,
    const short* __restrict__ P2, float* __restrict__ out) {
  extern __shared__ char sm[];
  char*  we     = sm;                          // [64][264 shorts], 528B stride
  char*  sB     = sm + 33792;                  // [256 d][40 shorts], 80B stride (KK=32)
  float* sDom   = (float*)(sm + 54272);
  float* sMask  = (float*)(sm + 75008);
  float* sScale = (float*)(sm + 76032);
  const int t  = threadIdx.x;
  const int b  = blockIdx.x >> 2;
  const int i0 = (blockIdx.x & 3) * 64;

  for (int x = t; x < 72 * 72; x += 512) sDom[x] = domain[x];
  if (t < 256) sMask[t] = seqmask[b * 256 + t];
  __syncthreads();

  // ---- phase 1: weight numerators (exp(w)+EPS for valid, 0 otherwise); row sums ----
  {
    const int r = t >> 3, q = t & 7;           // 8 threads per row, 64 rows
    const int ii = i0 + r;
    const float mI = sMask[ii];
    const size_t rowbase = ((size_t)b * 256 + ii) * 256;
    float rs = 0.f;
    #pragma unroll 4
    for (int jj = 0; jj < 8; ++jj) {
      int j = q * 4 + jj * 32;
      f32x4 dv = *(const f32x4*)(dist + rowbase + j);
      f32x4 bv = *(const f32x4*)(bear + rowbase + j);
      f32x4 hv = *(const f32x4*)(head + rowbase + j);
      bf16x4 pk;
      #pragma unroll
      for (int e = 0; e < 4; ++e) {
        int je = j + e;
        int i1 = (int)fminf(fmaxf(floorf((hv[e] + 2.5f) * 0.2f), 0.f), 71.f);
        int i2 = (int)fminf(fmaxf(floorf((bv[e] + 2.5f) * 0.2f), 0.f), 71.f);
        float w = fmaxf(sDom[i1 * 72 + i2] - dv[e], 0.f);
        bool valid = (ii != je) && (mI != 0.f) && (sMask[je] != 0.f);
        float ev = 0.f;
        if (valid) {
          float ex = (w > 0.f) ? __expf(w) : 0.f;
          rs += ex;
          ev = ex + EPSC;
        }
        pk[e] = f2bf(ev);
      }
      *(bf16x4*)(we + r * 528 + j * 2) = pk;
    }
    rs += __shfl_xor(rs, 1, 64);
    rs += __shfl_xor(rs, 2, 64);
    rs += __shfl_xor(rs, 4, 64);
    if (q == 0) sScale[r] = 1.0f / (rs + 257.0f * EPSC);
  }

  // ---- phase 2: out_tile = (numerators @ P1T) * rowscale + P2 ----
  const int wid = t >> 6, l = t & 63;
  const int wm = wid >> 2, wnv = wid & 3;      // wave tile 32 rows x 64 cols
  const int lr = l & 15, lg = l >> 4;
  f32x4 acc[2][4] = {};

  for (int kk = 0; kk < 256; kk += 32) {
    __syncthreads();                           // phase1 writes / prev chunk consumed
    #pragma unroll
    for (int p = 0; p < 2; ++p) {
      int z = t + 512 * p;                     // 0..1023 : d = z>>2, slot = z&3
      int d = z >> 2, s = z & 3;
      bf16x8 v = *(const bf16x8*)(P1T + (size_t)b * 65536 + (size_t)d * 256 + kk + s * 8);
      *(bf16x8*)(sB + d * 80 + s * 16) = v;
    }
    __syncthreads();
    bf16x8 a[2], bb[4];
    #pragma unroll
    for (int m = 0; m < 2; ++m) {
      int row = wm * 32 + m * 16 + lr;
      a[m] = *(const bf16x8*)(we + row * 528 + kk * 2 + lg * 16);
    }
    #pragma unroll
    for (int n = 0; n < 4; ++n) {
      int d = wnv * 64 + n * 16 + lr;
      bb[n] = *(const bf16x8*)(sB + d * 80 + lg * 16);
    }
    #pragma unroll
    for (int m = 0; m < 2; ++m) {
      #pragma unroll
      for (int n = 0; n < 4; ++n)
        acc[m][n] = __builtin_amdgcn_mfma_f32_16x16x32_bf16(a[m], bb[n], acc[m][n], 0, 0, 0);
    }
  }

  // epilogue
  #pragma unroll
  for (int m = 0; m < 2; ++m) {
    int rl = wm * 32 + m * 16 + lg * 4;
    #pragma unroll
    for (int n = 0; n < 4; ++n) {
      int d = wnv * 64 + n * 16 + lr;
      #pragma unroll
      for (int r = 0; r < 4; ++r) {
        int row = rl + r;
        float val = acc[m][n][r] * sScale[row]
                  + bf2f((unsigned short)P2[(size_t)b * 65536 + (size_t)(i0 + row) * 256 + d]);
        out[((size_t)b * 256 + i0 + row) * 256 + d] = val;
      }
    }
  }
}

extern "C" void kernel_launch(void* const* d_in, const int* in_sizes, int n_in,
                              void* d_out, int out_size, void* d_ws, size_t ws_size,
                              hipStream_t stream) {
  const float* hidden  = (const float*)d_in[0];
  const float* dist    = (const float*)d_in[1];
  const float* bear    = (const float*)d_in[2];
  const float* head    = (const float*)d_in[3];
  const float* seqmask = (const float*)d_in[4];
  const float* domain  = (const float*)d_in[5];
  const float* W       = (const float*)d_in[6];
  const float* bias    = (const float*)d_in[7];
  float* out = (float*)d_out;

  char* ws = (char*)d_ws;
  short* GbT = (short*)ws;                                   // 256 KB
  short* P1T = (short*)(ws + (1u << 20));                    // 32 MB
  short* P2  = (short*)(ws + (1u << 20) + (32u << 20));      // 32 MB

  k0_pack<<<512, 256, 0, stream>>>(W, GbT);
  k1_proj<<<1024, 512, 108544, stream>>>(hidden, GbT, bias, P1T, P2);
  k2_attn<<<1024, 512, 76288, stream>>>(dist, bear, head, seqmask, domain, P1T, P2, out);
}

// Round 3
// 138.821 us; speedup vs baseline: 1.0874x; 1.0359x over previous
//
#include <hip/hip_runtime.h>
#include <hip/hip_bf16.h>

// spatial_attention: out = [scaled_weights | H] @ Wcat^T + bias   (K = 512 concat GEMM)
//   K0 : Wbf[d][k] = bf16(W[d][k]), 256 x 512                      (512 KB)
//   K1 : P1T[b][d][j] = bf16( sum_k H[b,j,k] * W[d,k<256] )        (32 MB, transposed)
//   K2a: weBuf[b][i][j] = bf16( scaled softmax-ish weights )       (32 MB, pre-scaled!)
//   K2b: out[b,i,d] = sum_{k<256} weBuf[b,i,k]*P1T[b,d,k]
//                   + sum_{k>=256} bf16(H[b,i,k-256])*Wbf[d,k] + bias[d]
// Workspace: Wbf 512KB @0 ; P1T 32MB @1MB ; weBuf 32MB @33MB  (65MB total)

typedef __attribute__((ext_vector_type(4))) float  f32x4;
typedef __attribute__((ext_vector_type(8))) short  bf16x8;
typedef __attribute__((ext_vector_type(4))) short  bf16x4;

#define EPSC 1e-14f

__device__ __forceinline__ short f2bf(float v) {
  __hip_bfloat16 h = __float2bfloat16(v);
  return *reinterpret_cast<short*>(&h);
}

// ---------------- K0: W fp32 -> bf16, same layout (256 x 512) ----------------
__global__ void k0_pack(const float* __restrict__ W, short* __restrict__ Wbf) {
  int idx = blockIdx.x * 256 + threadIdx.x;     // 128 blocks x 256 thr, 4 elems each
  f32x4 v = *(const f32x4*)(W + (size_t)idx * 4);
  bf16x4 pk;
  pk[0] = f2bf(v[0]); pk[1] = f2bf(v[1]); pk[2] = f2bf(v[2]); pk[3] = f2bf(v[3]);
  *(bf16x4*)(Wbf + (size_t)idx * 4) = pk;
}

// ---------------- K1: P1T = (H @ W1^T)^T, grid 1024 (64 j-rows), block 512 ----------------
// LDS: sA[64 j][144B] = 9216 ; sB[256 d][144B] = 36864  -> 46080 B => 3 blocks/CU
__global__ __launch_bounds__(512) void k1_proj(
    const float* __restrict__ H, const short* __restrict__ Wbf,
    short* __restrict__ P1T) {
  extern __shared__ char sm[];
  char* sA = sm;                 // 64 rows x 64 k bf16, 144B stride
  char* sB = sm + 9216;          // 256 d x 64 k bf16, 144B stride
  const int t  = threadIdx.x;
  const int n0 = blockIdx.x * 64;
  const int b  = n0 >> 8;
  const int jb = n0 & 255;

  const int wid = t >> 6, l = t & 63;
  const int wn = wid >> 2, wc = wid & 3;      // 2 x 32 j-rows, 4 x 64 d-cols
  const int lr = l & 15, lg = l >> 4;
  f32x4 acc[2][4] = {};

  for (int kk = 0; kk < 256; kk += 64) {
    __syncthreads();
    // stage A: H rows fp32 -> bf16  (64 j x 64 k)
    #pragma unroll
    for (int p = 0; p < 2; ++p) {
      int q = t + 512 * p;                    // 0..1023 : j = q>>4, seg = q&15
      int j = q >> 4, seg = q & 15;
      f32x4 hv = *(const f32x4*)(H + ((size_t)(n0 + j)) * 256 + kk + seg * 4);
      bf16x4 pk;
      pk[0] = f2bf(hv[0]); pk[1] = f2bf(hv[1]); pk[2] = f2bf(hv[2]); pk[3] = f2bf(hv[3]);
      *(bf16x4*)(sA + j * 144 + seg * 8) = pk;
    }
    // stage B: Wbf first half (256 d x 64 k)
    #pragma unroll
    for (int p = 0; p < 4; ++p) {
      int z = t + 512 * p;                    // 0..2047 : d = z>>3, s = z&7
      int d = z >> 3, s = z & 7;
      bf16x8 v = *(const bf16x8*)(Wbf + (size_t)d * 512 + kk + s * 8);
      *(bf16x8*)(sB + d * 144 + s * 16) = v;
    }
    __syncthreads();
    #pragma unroll
    for (int sub = 0; sub < 2; ++sub) {
      bf16x8 a[2], bb[4];
      #pragma unroll
      for (int m = 0; m < 2; ++m) {
        int row = wn * 32 + m * 16 + lr;
        a[m] = *(const bf16x8*)(sA + row * 144 + sub * 64 + lg * 16);
      }
      #pragma unroll
      for (int f = 0; f < 4; ++f) {
        int d = wc * 64 + f * 16 + lr;
        bb[f] = *(const bf16x8*)(sB + d * 144 + sub * 64 + lg * 16);
      }
      #pragma unroll
      for (int m = 0; m < 2; ++m) {
        #pragma unroll
        for (int f = 0; f < 4; ++f)
          acc[m][f] = __builtin_amdgcn_mfma_f32_16x16x32_bf16(a[m], bb[f], acc[m][f], 0, 0, 0);
      }
    }
  }

  // epilogue: P1T[b][d][jb + j]
  #pragma unroll
  for (int m = 0; m < 2; ++m) {
    int jl = wn * 32 + m * 16 + lg * 4;
    #pragma unroll
    for (int f = 0; f < 4; ++f) {
      int d = wc * 64 + f * 16 + lr;
      f32x4 v = acc[m][f];
      bf16x4 pk;
      pk[0] = f2bf(v[0]); pk[1] = f2bf(v[1]); pk[2] = f2bf(v[2]); pk[3] = f2bf(v[3]);
      *(bf16x4*)(P1T + (size_t)b * 65536 + (size_t)d * 256 + jb + jl) = pk;
    }
  }
}

// ---------------- K2a: pre-scaled weights, grid 1024 (64 rows each), block 512 ----------------
// LDS: dom 20736 + mask 1024 = 21760 B => high occupancy. One wave per row (8 rows/wave).
__global__ __launch_bounds__(512) void k2a_weights(
    const float* __restrict__ dist, const float* __restrict__ bear,
    const float* __restrict__ head, const float* __restrict__ seqmask,
    const float* __restrict__ domain, short* __restrict__ weBuf) {
  extern __shared__ char sm[];
  float* sDom  = (float*)sm;
  float* sMask = (float*)(sm + 20736);
  const int t  = threadIdx.x;
  const int b  = blockIdx.x >> 2;
  const int i0 = (blockIdx.x & 3) * 64;

  for (int x = t; x < 72 * 72; x += 512) sDom[x] = domain[x];
  if (t < 256) sMask[t] = seqmask[b * 256 + t];
  __syncthreads();

  const int w = t >> 6, l = t & 63;
  const int j0 = l * 4;

  #pragma unroll 2
  for (int rr = 0; rr < 8; ++rr) {
    const int i = i0 + w * 8 + rr;
    const float mI = sMask[i];
    const size_t base = ((size_t)b * 256 + i) * 256;
    f32x4 dv = *(const f32x4*)(dist + base + j0);
    f32x4 bv = *(const f32x4*)(bear + base + j0);
    f32x4 hv = *(const f32x4*)(head + base + j0);
    float ev[4];
    float rs = 0.f;
    #pragma unroll
    for (int e = 0; e < 4; ++e) {
      int je = j0 + e;
      int i1 = (int)fminf(fmaxf(floorf((hv[e] + 2.5f) * 0.2f), 0.f), 71.f);
      int i2 = (int)fminf(fmaxf(floorf((bv[e] + 2.5f) * 0.2f), 0.f), 71.f);
      float wv = fmaxf(sDom[i1 * 72 + i2] - dv[e], 0.f);
      bool valid = (i != je) && (mI != 0.f) && (sMask[je] != 0.f);
      float x = 0.f;
      if (valid) {
        float ex = (wv > 0.f) ? __expf(wv) : 0.f;
        rs += ex;
        x = ex + EPSC;
      }
      ev[e] = x;
    }
    // full-wave sum of rs
    rs += __shfl_xor(rs, 1, 64);
    rs += __shfl_xor(rs, 2, 64);
    rs += __shfl_xor(rs, 4, 64);
    rs += __shfl_xor(rs, 8, 64);
    rs += __shfl_xor(rs, 16, 64);
    rs += __shfl_xor(rs, 32, 64);
    const float scale = 1.0f / (rs + 257.0f * EPSC);
    bf16x4 pk;
    pk[0] = f2bf(ev[0] * scale); pk[1] = f2bf(ev[1] * scale);
    pk[2] = f2bf(ev[2] * scale); pk[3] = f2bf(ev[3] * scale);
    *(bf16x4*)(weBuf + base + j0) = pk;
  }
}

// ---------------- K2b: out = [weBuf | bf16(H)] @ Wcat + bias, K=512 ----------------
// grid 512 (b = blk>>1, i0 = (blk&1)*128), block 512
// LDS: sA[128][144]=18432 ; sB[256][144]=36864 ; bias 1024 -> 56320 B => 2 blocks/CU
__global__ __launch_bounds__(512) void k2b_gemm(
    const short* __restrict__ weBuf, const float* __restrict__ H,
    const short* __restrict__ P1T, const short* __restrict__ Wbf,
    const float* __restrict__ bias, float* __restrict__ out) {
  extern __shared__ char sm[];
  char*  sA    = sm;                 // 128 rows x 64 k bf16, 144B stride
  char*  sB    = sm + 18432;         // 256 d  x 64 k bf16, 144B stride
  float* sBias = (float*)(sm + 18432 + 36864);
  const int t  = threadIdx.x;
  const int b  = blockIdx.x >> 1;
  const int i0 = (blockIdx.x & 1) * 128;

  if (t < 256) sBias[t] = bias[t];

  const int wid = t >> 6, l = t & 63;
  const int wm = wid >> 1, wn = wid & 1;       // 4 x 32 rows, 2 x 128 d
  const int lr = l & 15, lg = l >> 4;
  f32x4 acc[2][8] = {};

  for (int kk = 0; kk < 512; kk += 64) {
    __syncthreads();
    // stage A: 128 rows x 64 k
    if (kk < 256) {
      #pragma unroll
      for (int p = 0; p < 2; ++p) {
        int z = t + 512 * p;                   // 0..1023 : row = z>>3, s = z&7
        int row = z >> 3, s = z & 7;
        bf16x8 v = *(const bf16x8*)(weBuf + ((size_t)b * 256 + i0 + row) * 256 + kk + s * 8);
        *(bf16x8*)(sA + row * 144 + s * 16) = v;
      }
    } else {
      #pragma unroll
      for (int p = 0; p < 2; ++p) {
        int z = t + 512 * p;
        int row = z >> 3, s = z & 7;
        const float* src = H + ((size_t)b * 256 + i0 + row) * 256 + (kk - 256) + s * 8;
        f32x4 h0 = *(const f32x4*)(src);
        f32x4 h1 = *(const f32x4*)(src + 4);
        bf16x8 pk;
        pk[0] = f2bf(h0[0]); pk[1] = f2bf(h0[1]); pk[2] = f2bf(h0[2]); pk[3] = f2bf(h0[3]);
        pk[4] = f2bf(h1[0]); pk[5] = f2bf(h1[1]); pk[6] = f2bf(h1[2]); pk[7] = f2bf(h1[3]);
        *(bf16x8*)(sA + row * 144 + s * 16) = pk;
      }
    }
    // stage B: 256 d x 64 k
    #pragma unroll
    for (int p = 0; p < 4; ++p) {
      int z = t + 512 * p;                     // 0..2047 : d = z>>3, s = z&7
      int d = z >> 3, s = z & 7;
      bf16x8 v;
      if (kk < 256) v = *(const bf16x8*)(P1T + (size_t)b * 65536 + (size_t)d * 256 + kk + s * 8);
      else          v = *(const bf16x8*)(Wbf + (size_t)d * 512 + kk + s * 8);
      *(bf16x8*)(sB + d * 144 + s * 16) = v;
    }
    __syncthreads();
    #pragma unroll
    for (int sub = 0; sub < 2; ++sub) {
      bf16x8 a[2], bb[8];
      #pragma unroll
      for (int m = 0; m < 2; ++m) {
        int row = wm * 32 + m * 16 + lr;
        a[m] = *(const bf16x8*)(sA + row * 144 + sub * 64 + lg * 16);
      }
      #pragma unroll
      for (int n = 0; n < 8; ++n) {
        int d = wn * 128 + n * 16 + lr;
        bb[n] = *(const bf16x8*)(sB + d * 144 + sub * 64 + lg * 16);
      }
      #pragma unroll
      for (int m = 0; m < 2; ++m) {
        #pragma unroll
        for (int n = 0; n < 8; ++n)
          acc[m][n] = __builtin_amdgcn_mfma_f32_16x16x32_bf16(a[m], bb[n], acc[m][n], 0, 0, 0);
      }
    }
  }

  // epilogue
  #pragma unroll
  for (int m = 0; m < 2; ++m) {
    int rl = wm * 32 + m * 16 + lg * 4;
    #pragma unroll
    for (int n = 0; n < 8; ++n) {
      int d = wn * 128 + n * 16 + lr;
      float bs = sBias[d];
      #pragma unroll
      for (int r = 0; r < 4; ++r) {
        int row = rl + r;
        out[((size_t)b * 256 + i0 + row) * 256 + d] = acc[m][n][r] + bs;
      }
    }
  }
}

extern "C" void kernel_launch(void* const* d_in, const int* in_sizes, int n_in,
                              void* d_out, int out_size, void* d_ws, size_t ws_size,
                              hipStream_t stream) {
  const float* hidden  = (const float*)d_in[0];
  const float* dist    = (const float*)d_in[1];
  const float* bear    = (const float*)d_in[2];
  const float* head    = (const float*)d_in[3];
  const float* seqmask = (const float*)d_in[4];
  const float* domain  = (const float*)d_in[5];
  const float* W       = (const float*)d_in[6];
  const float* bias    = (const float*)d_in[7];
  float* out = (float*)d_out;

  char* ws = (char*)d_ws;
  short* Wbf   = (short*)ws;                                 // 512 KB
  short* P1T   = (short*)(ws + (1u << 20));                  // 32 MB
  short* weBuf = (short*)(ws + (1u << 20) + (32u << 20));    // 32 MB

  k0_pack<<<128, 256, 0, stream>>>(W, Wbf);
  k1_proj<<<1024, 512, 46080, stream>>>(hidden, Wbf, P1T);
  k2a_weights<<<1024, 512, 21760, stream>>>(dist, bear, head, seqmask, domain, weBuf);
  k2b_gemm<<<512, 512, 56320, stream>>>(weBuf, hidden, P1T, Wbf, bias, out);
}

// Round 4
// 133.608 us; speedup vs baseline: 1.1298x; 1.0390x over previous
//
#include <hip/hip_runtime.h>
#include <hip/hip_bf16.h>

// spatial_attention: out = [scaled_weights | H] @ Wcat^T + bias   (K = 512 concat GEMM)
//   K0 : Wbf[d][k] = bf16(W[d][k]), 256 x 512                      (512 KB)
//   K1 : P1T[b][d][j] = bf16( sum_k H[b,j,k] * W[d,k<256] )        (32 MB, transposed)
//   K2a: weBuf[b][i][j] = bf16( scaled softmax-ish weights )       (32 MB, pre-scaled!)
//   K2b: out[b,i,d] = sum_{k<256} weBuf[b,i,k]*P1T[b,d,k]
//                   + sum_{k>=256} bf16(H[b,i,k-256])*Wbf[d,k] + bias[d]
// Workspace: Wbf 512KB @0 ; P1T 32MB @1MB ; weBuf 32MB @33MB  (65MB total)

typedef __attribute__((ext_vector_type(4))) float  f32x4;
typedef __attribute__((ext_vector_type(8))) short  bf16x8;
typedef __attribute__((ext_vector_type(4))) short  bf16x4;

#define EPSC 1e-14f

__device__ __forceinline__ short f2bf(float v) {
  __hip_bfloat16 h = __float2bfloat16(v);
  return *reinterpret_cast<short*>(&h);
}

// ---------------- K0: W fp32 -> bf16, same layout (256 x 512) ----------------
__global__ void k0_pack(const float* __restrict__ W, short* __restrict__ Wbf) {
  int idx = blockIdx.x * 256 + threadIdx.x;
  f32x4 v = *(const f32x4*)(W + (size_t)idx * 4);
  bf16x4 pk;
  pk[0] = f2bf(v[0]); pk[1] = f2bf(v[1]); pk[2] = f2bf(v[2]); pk[3] = f2bf(v[3]);
  *(bf16x4*)(Wbf + (size_t)idx * 4) = pk;
}

// ---------------- K1: P1T = (H @ W1^T)^T, grid 1024 (64 j-rows), block 512 ----------------
__global__ __launch_bounds__(512) void k1_proj(
    const float* __restrict__ H, const short* __restrict__ Wbf,
    short* __restrict__ P1T) {
  extern __shared__ char sm[];
  char* sA = sm;                 // 64 rows x 64 k bf16, 144B stride
  char* sB = sm + 9216;          // 256 d x 64 k bf16, 144B stride
  const int t  = threadIdx.x;
  const int n0 = blockIdx.x * 64;
  const int b  = n0 >> 8;
  const int jb = n0 & 255;

  const int wid = t >> 6, l = t & 63;
  const int wn = wid >> 2, wc = wid & 3;
  const int lr = l & 15, lg = l >> 4;
  f32x4 acc[2][4] = {};

  for (int kk = 0; kk < 256; kk += 64) {
    __syncthreads();
    #pragma unroll
    for (int p = 0; p < 2; ++p) {
      int q = t + 512 * p;
      int j = q >> 4, seg = q & 15;
      f32x4 hv = *(const f32x4*)(H + ((size_t)(n0 + j)) * 256 + kk + seg * 4);
      bf16x4 pk;
      pk[0] = f2bf(hv[0]); pk[1] = f2bf(hv[1]); pk[2] = f2bf(hv[2]); pk[3] = f2bf(hv[3]);
      *(bf16x4*)(sA + j * 144 + seg * 8) = pk;
    }
    #pragma unroll
    for (int p = 0; p < 4; ++p) {
      int z = t + 512 * p;
      int d = z >> 3, s = z & 7;
      bf16x8 v = *(const bf16x8*)(Wbf + (size_t)d * 512 + kk + s * 8);
      *(bf16x8*)(sB + d * 144 + s * 16) = v;
    }
    __syncthreads();
    #pragma unroll
    for (int sub = 0; sub < 2; ++sub) {
      bf16x8 a[2], bb[4];
      #pragma unroll
      for (int m = 0; m < 2; ++m) {
        int row = wn * 32 + m * 16 + lr;
        a[m] = *(const bf16x8*)(sA + row * 144 + sub * 64 + lg * 16);
      }
      #pragma unroll
      for (int f = 0; f < 4; ++f) {
        int d = wc * 64 + f * 16 + lr;
        bb[f] = *(const bf16x8*)(sB + d * 144 + sub * 64 + lg * 16);
      }
      #pragma unroll
      for (int m = 0; m < 2; ++m) {
        #pragma unroll
        for (int f = 0; f < 4; ++f)
          acc[m][f] = __builtin_amdgcn_mfma_f32_16x16x32_bf16(a[m], bb[f], acc[m][f], 0, 0, 0);
      }
    }
  }

  #pragma unroll
  for (int m = 0; m < 2; ++m) {
    int jl = wn * 32 + m * 16 + lg * 4;
    #pragma unroll
    for (int f = 0; f < 4; ++f) {
      int d = wc * 64 + f * 16 + lr;
      f32x4 v = acc[m][f];
      bf16x4 pk;
      pk[0] = f2bf(v[0]); pk[1] = f2bf(v[1]); pk[2] = f2bf(v[2]); pk[3] = f2bf(v[3]);
      *(bf16x4*)(P1T + (size_t)b * 65536 + (size_t)d * 256 + jb + jl) = pk;
    }
  }
}

// ---------------- K2a: pre-scaled weights, grid 2048 (32 rows each), block 256 ----------------
// One row per 8 lanes. ALL 24 loads issued upfront (deep MLP); single 3-shfl reduce.
// LDS: dom 20736 + mask 1024 = 21760 B.
__global__ __launch_bounds__(256) void k2a_weights(
    const float* __restrict__ dist, const float* __restrict__ bear,
    const float* __restrict__ head, const float* __restrict__ seqmask,
    const float* __restrict__ domain, short* __restrict__ weBuf) {
  extern __shared__ char sm[];
  float* sDom  = (float*)sm;
  float* sMask = (float*)(sm + 20736);
  const int t  = threadIdx.x;
  const int b  = blockIdx.x >> 3;
  const int i0 = (blockIdx.x & 7) * 32;

  for (int x = t; x < 72 * 72; x += 256) sDom[x] = domain[x];
  sMask[t] = seqmask[b * 256 + t];
  __syncthreads();

  const int r = t >> 3, q = t & 7;            // 32 rows x 8 lanes
  const int i = i0 + r;
  const float mI = sMask[i];
  const size_t base = ((size_t)b * 256 + i) * 256;
  const int j0 = q * 4;

  // issue all loads upfront: 24 x f32x4 in flight per thread
  f32x4 dv[8], bv[8], hv[8];
  #pragma unroll
  for (int c = 0; c < 8; ++c) {
    dv[c] = *(const f32x4*)(dist + base + j0 + c * 32);
    bv[c] = *(const f32x4*)(bear + base + j0 + c * 32);
    hv[c] = *(const f32x4*)(head + base + j0 + c * 32);
  }

  float ev[8][4];
  float rs = 0.f;
  #pragma unroll
  for (int c = 0; c < 8; ++c) {
    #pragma unroll
    for (int e = 0; e < 4; ++e) {
      int je = j0 + c * 32 + e;
      int i1 = (int)fminf(fmaxf(floorf((hv[c][e] + 2.5f) * 0.2f), 0.f), 71.f);
      int i2 = (int)fminf(fmaxf(floorf((bv[c][e] + 2.5f) * 0.2f), 0.f), 71.f);
      float wv = fmaxf(sDom[i1 * 72 + i2] - dv[c][e], 0.f);
      bool valid = (i != je) && (mI != 0.f) && (sMask[je] != 0.f);
      float ex = (wv > 0.f) ? __expf(wv) : 0.f;
      ex = valid ? ex : 0.f;
      rs += ex;
      ev[c][e] = valid ? (ex + EPSC) : 0.f;
    }
  }

  // single 3-deep reduce across the 8 lanes of this row
  rs += __shfl_xor(rs, 1, 64);
  rs += __shfl_xor(rs, 2, 64);
  rs += __shfl_xor(rs, 4, 64);
  const float scale = 1.0f / (rs + 257.0f * EPSC);

  #pragma unroll
  for (int c = 0; c < 8; ++c) {
    bf16x4 pk;
    pk[0] = f2bf(ev[c][0] * scale); pk[1] = f2bf(ev[c][1] * scale);
    pk[2] = f2bf(ev[c][2] * scale); pk[3] = f2bf(ev[c][3] * scale);
    *(bf16x4*)(weBuf + base + j0 + c * 32) = pk;
  }
}

// ---------------- K2b: out = [weBuf | bf16(H)] @ Wcat + bias, K=512 ----------------
__global__ __launch_bounds__(512) void k2b_gemm(
    const short* __restrict__ weBuf, const float* __restrict__ H,
    const short* __restrict__ P1T, const short* __restrict__ Wbf,
    const float* __restrict__ bias, float* __restrict__ out) {
  extern __shared__ char sm[];
  char*  sA    = sm;                 // 128 rows x 64 k bf16, 144B stride
  char*  sB    = sm + 18432;         // 256 d  x 64 k bf16, 144B stride
  float* sBias = (float*)(sm + 18432 + 36864);
  const int t  = threadIdx.x;
  const int b  = blockIdx.x >> 1;
  const int i0 = (blockIdx.x & 1) * 128;

  if (t < 256) sBias[t] = bias[t];

  const int wid = t >> 6, l = t & 63;
  const int wm = wid >> 1, wn = wid & 1;
  const int lr = l & 15, lg = l >> 4;
  f32x4 acc[2][8] = {};

  for (int kk = 0; kk < 512; kk += 64) {
    __syncthreads();
    if (kk < 256) {
      #pragma unroll
      for (int p = 0; p < 2; ++p) {
        int z = t + 512 * p;
        int row = z >> 3, s = z & 7;
        bf16x8 v = *(const bf16x8*)(weBuf + ((size_t)b * 256 + i0 + row) * 256 + kk + s * 8);
        *(bf16x8*)(sA + row * 144 + s * 16) = v;
      }
    } else {
      #pragma unroll
      for (int p = 0; p < 2; ++p) {
        int z = t + 512 * p;
        int row = z >> 3, s = z & 7;
        const float* src = H + ((size_t)b * 256 + i0 + row) * 256 + (kk - 256) + s * 8;
        f32x4 h0 = *(const f32x4*)(src);
        f32x4 h1 = *(const f32x4*)(src + 4);
        bf16x8 pk;
        pk[0] = f2bf(h0[0]); pk[1] = f2bf(h0[1]); pk[2] = f2bf(h0[2]); pk[3] = f2bf(h0[3]);
        pk[4] = f2bf(h1[0]); pk[5] = f2bf(h1[1]); pk[6] = f2bf(h1[2]); pk[7] = f2bf(h1[3]);
        *(bf16x8*)(sA + row * 144 + s * 16) = pk;
      }
    }
    #pragma unroll
    for (int p = 0; p < 4; ++p) {
      int z = t + 512 * p;
      int d = z >> 3, s = z & 7;
      bf16x8 v;
      if (kk < 256) v = *(const bf16x8*)(P1T + (size_t)b * 65536 + (size_t)d * 256 + kk + s * 8);
      else          v = *(const bf16x8*)(Wbf + (size_t)d * 512 + kk + s * 8);
      *(bf16x8*)(sB + d * 144 + s * 16) = v;
    }
    __syncthreads();
    #pragma unroll
    for (int sub = 0; sub < 2; ++sub) {
      bf16x8 a[2], bb[8];
      #pragma unroll
      for (int m = 0; m < 2; ++m) {
        int row = wm * 32 + m * 16 + lr;
        a[m] = *(const bf16x8*)(sA + row * 144 + sub * 64 + lg * 16);
      }
      #pragma unroll
      for (int n = 0; n < 8; ++n) {
        int d = wn * 128 + n * 16 + lr;
        bb[n] = *(const bf16x8*)(sB + d * 144 + sub * 64 + lg * 16);
      }
      #pragma unroll
      for (int m = 0; m < 2; ++m) {
        #pragma unroll
        for (int n = 0; n < 8; ++n)
          acc[m][n] = __builtin_amdgcn_mfma_f32_16x16x32_bf16(a[m], bb[n], acc[m][n], 0, 0, 0);
      }
    }
  }

  #pragma unroll
  for (int m = 0; m < 2; ++m) {
    int rl = wm * 32 + m * 16 + lg * 4;
    #pragma unroll
    for (int n = 0; n < 8; ++n) {
      int d = wn * 128 + n * 16 + lr;
      float bs = sBias[d];
      #pragma unroll
      for (int r = 0; r < 4; ++r) {
        int row = rl + r;
        out[((size_t)b * 256 + i0 + row) * 256 + d] = acc[m][n][r] + bs;
      }
    }
  }
}

extern "C" void kernel_launch(void* const* d_in, const int* in_sizes, int n_in,
                              void* d_out, int out_size, void* d_ws, size_t ws_size,
                              hipStream_t stream) {
  const float* hidden  = (const float*)d_in[0];
  const float* dist    = (const float*)d_in[1];
  const float* bear    = (const float*)d_in[2];
  const float* head    = (const float*)d_in[3];
  const float* seqmask = (const float*)d_in[4];
  const float* domain  = (const float*)d_in[5];
  const float* W       = (const float*)d_in[6];
  const float* bias    = (const float*)d_in[7];
  float* out = (float*)d_out;

  char* ws = (char*)d_ws;
  short* Wbf   = (short*)ws;                                 // 512 KB
  short* P1T   = (short*)(ws + (1u << 20));                  // 32 MB
  short* weBuf = (short*)(ws + (1u << 20) + (32u << 20));    // 32 MB

  k0_pack<<<128, 256, 0, stream>>>(W, Wbf);
  k1_proj<<<1024, 512, 46080, stream>>>(hidden, Wbf, P1T);
  k2a_weights<<<2048, 256, 21760, stream>>>(dist, bear, head, seqmask, domain, weBuf);
  k2b_gemm<<<512, 512, 56320, stream>>>(weBuf, hidden, P1T, Wbf, bias, out);
}

// Round 5
// 122.497 us; speedup vs baseline: 1.2323x; 1.0907x over previous
//
#include <hip/hip_runtime.h>
#include <hip/hip_bf16.h>

// spatial_attention: out = [softmax_weights | H] @ Wcat^T + bias
//   K0 : Wbf = bf16(W)                                   (512 KB)
//   K1 : P1T[b][d][j] = bf16( (H W1^T)[j][d] )           (32 MB, transposed)
//   K2 : fused — weight numerators computed IN A-FRAGMENT REGISTERS,
//        MFMA vs P1T (K=256), mid-kernel row-scale of acc, then H@W2 (K=256), +bias.
// Workspace: Wbf 512KB @0 ; P1T 32MB @1MB  (33MB total)

typedef __attribute__((ext_vector_type(4))) float  f32x4;
typedef __attribute__((ext_vector_type(8))) short  bf16x8;
typedef __attribute__((ext_vector_type(4))) short  bf16x4;

#define EPSC 1e-14f

__device__ __forceinline__ short f2bf(float v) {
  __hip_bfloat16 h = __float2bfloat16(v);
  return *reinterpret_cast<short*>(&h);
}

// ---------------- K0: W fp32 -> bf16, same layout (256 x 512) ----------------
__global__ void k0_pack(const float* __restrict__ W, short* __restrict__ Wbf) {
  int idx = blockIdx.x * 256 + threadIdx.x;
  f32x4 v = *(const f32x4*)(W + (size_t)idx * 4);
  bf16x4 pk;
  pk[0] = f2bf(v[0]); pk[1] = f2bf(v[1]); pk[2] = f2bf(v[2]); pk[3] = f2bf(v[3]);
  *(bf16x4*)(Wbf + (size_t)idx * 4) = pk;
}

// ---------------- K1: P1T = (H @ W1^T)^T, grid 1024 (64 j-rows), block 512 ----------------
__global__ __launch_bounds__(512) void k1_proj(
    const float* __restrict__ H, const short* __restrict__ Wbf,
    short* __restrict__ P1T) {
  extern __shared__ char sm[];
  char* sA = sm;                 // 64 rows x 64 k bf16, 144B stride
  char* sB = sm + 9216;          // 256 d x 64 k bf16, 144B stride
  const int t  = threadIdx.x;
  const int n0 = blockIdx.x * 64;
  const int b  = n0 >> 8;
  const int jb = n0 & 255;

  const int wid = t >> 6, l = t & 63;
  const int wn = wid >> 2, wc = wid & 3;
  const int lr = l & 15, lg = l >> 4;
  f32x4 acc[2][4] = {};

  for (int kk = 0; kk < 256; kk += 64) {
    __syncthreads();
    #pragma unroll
    for (int p = 0; p < 2; ++p) {
      int q = t + 512 * p;
      int j = q >> 4, seg = q & 15;
      f32x4 hv = *(const f32x4*)(H + ((size_t)(n0 + j)) * 256 + kk + seg * 4);
      bf16x4 pk;
      pk[0] = f2bf(hv[0]); pk[1] = f2bf(hv[1]); pk[2] = f2bf(hv[2]); pk[3] = f2bf(hv[3]);
      *(bf16x4*)(sA + j * 144 + seg * 8) = pk;
    }
    #pragma unroll
    for (int p = 0; p < 4; ++p) {
      int z = t + 512 * p;
      int d = z >> 3, s = z & 7;
      bf16x8 v = *(const bf16x8*)(Wbf + (size_t)d * 512 + kk + s * 8);
      *(bf16x8*)(sB + d * 144 + s * 16) = v;
    }
    __syncthreads();
    #pragma unroll
    for (int sub = 0; sub < 2; ++sub) {
      bf16x8 a[2], bb[4];
      #pragma unroll
      for (int m = 0; m < 2; ++m) {
        int row = wn * 32 + m * 16 + lr;
        a[m] = *(const bf16x8*)(sA + row * 144 + sub * 64 + lg * 16);
      }
      #pragma unroll
      for (int f = 0; f < 4; ++f) {
        int d = wc * 64 + f * 16 + lr;
        bb[f] = *(const bf16x8*)(sB + d * 144 + sub * 64 + lg * 16);
      }
      #pragma unroll
      for (int m = 0; m < 2; ++m) {
        #pragma unroll
        for (int f = 0; f < 4; ++f)
          acc[m][f] = __builtin_amdgcn_mfma_f32_16x16x32_bf16(a[m], bb[f], acc[m][f], 0, 0, 0);
      }
    }
  }

  #pragma unroll
  for (int m = 0; m < 2; ++m) {
    int jl = wn * 32 + m * 16 + lg * 4;
    #pragma unroll
    for (int f = 0; f < 4; ++f) {
      int d = wc * 64 + f * 16 + lr;
      f32x4 v = acc[m][f];
      bf16x4 pk;
      pk[0] = f2bf(v[0]); pk[1] = f2bf(v[1]); pk[2] = f2bf(v[2]); pk[3] = f2bf(v[3]);
      *(bf16x4*)(P1T + (size_t)b * 65536 + (size_t)d * 256 + jb + jl) = pk;
    }
  }
}

// ---------------- K2 fused: grid 512 (b = blk>>1, i0 = (blk&1)*128), block 512 ----------------
// 8 waves, each owns 16 rows x 256 d. Weight numerators -> A-frag registers directly.
// LDS: sB[256][144]=36864 ; sA[128][144]=18432 ; dom 20736 ; mask 1024 ; bias 1024 = 78080 B
__global__ __launch_bounds__(512, 4) void k2_fused(
    const float* __restrict__ dist, const float* __restrict__ bear,
    const float* __restrict__ head, const float* __restrict__ seqmask,
    const float* __restrict__ domain, const short* __restrict__ P1T,
    const short* __restrict__ Wbf, const float* __restrict__ H,
    const float* __restrict__ bias, float* __restrict__ out) {
  extern __shared__ char sm[];
  char*  sB    = sm;                            // [256 d][144B] bf16 k-chunk
  char*  sA    = sm + 36864;                    // [128 row][144B] bf16 (H half)
  float* sDom  = (float*)(sm + 55296);
  float* sMask = (float*)(sm + 76032);
  float* sBias = (float*)(sm + 77056);
  const int t  = threadIdx.x;
  const int b  = blockIdx.x >> 1;
  const int i0 = (blockIdx.x & 1) * 128;

  for (int x = t; x < 72 * 72; x += 512) sDom[x] = domain[x];
  if (t < 256) { sMask[t] = seqmask[b * 256 + t]; sBias[t] = bias[t]; }
  __syncthreads();

  const int wid = t >> 6, l = t & 63;
  const int lr = l & 15, lg = l >> 4;
  const int i  = i0 + wid * 16 + lr;            // this thread's weight row
  const float mI = sMask[i];
  const size_t base = ((size_t)b * 256 + i) * 256;

  f32x4 acc[16] = {};
  float rs = 0.f;

  // ---- first half: weights (regs) @ P1T (LDS), 4 chunks of K=64 ----
  for (int c = 0; c < 4; ++c) {
    const int kk = c * 64;
    // issue sB staging loads (held in regs, written after compute issues)
    bf16x8 st[4];
    #pragma unroll
    for (int p = 0; p < 4; ++p) {
      int z = t + 512 * p;                      // d = z>>3, s = z&7
      st[p] = *(const bf16x8*)(P1T + (size_t)b * 65536 + (size_t)(z >> 3) * 256 + kk + (z & 7) * 8);
    }
    // compute this chunk's A-fragments (2 subs x 8 elems), numerators only
    bf16x8 afrag[2];
    #pragma unroll
    for (int sub = 0; sub < 2; ++sub) {
      const int k0 = kk + sub * 32 + lg * 8;
      f32x4 d0 = *(const f32x4*)(dist + base + k0);
      f32x4 d1 = *(const f32x4*)(dist + base + k0 + 4);
      f32x4 b0 = *(const f32x4*)(bear + base + k0);
      f32x4 b1 = *(const f32x4*)(bear + base + k0 + 4);
      f32x4 h0 = *(const f32x4*)(head + base + k0);
      f32x4 h1 = *(const f32x4*)(head + base + k0 + 4);
      f32x4 m0 = *(const f32x4*)(sMask + k0);
      f32x4 m1 = *(const f32x4*)(sMask + k0 + 4);
      bf16x8 pk;
      #pragma unroll
      for (int e = 0; e < 4; ++e) {
        float f1 = fminf(fmaxf(floorf((h0[e] + 2.5f) * 0.2f), 0.f), 71.f);
        float f2 = fminf(fmaxf(floorf((b0[e] + 2.5f) * 0.2f), 0.f), 71.f);
        float wv = fmaxf(sDom[(int)(f1 * 72.f + f2)] - d0[e], 0.f);
        bool valid = (i != k0 + e) && (mI != 0.f) && (m0[e] != 0.f);
        float ex = (wv > 0.f) ? __expf(wv) : 0.f;
        ex = valid ? ex : 0.f;
        rs += ex;
        pk[e] = f2bf(valid ? (ex + EPSC) : 0.f);
      }
      #pragma unroll
      for (int e = 0; e < 4; ++e) {
        float f1 = fminf(fmaxf(floorf((h1[e] + 2.5f) * 0.2f), 0.f), 71.f);
        float f2 = fminf(fmaxf(floorf((b1[e] + 2.5f) * 0.2f), 0.f), 71.f);
        float wv = fmaxf(sDom[(int)(f1 * 72.f + f2)] - d1[e], 0.f);
        bool valid = (i != k0 + 4 + e) && (mI != 0.f) && (m1[e] != 0.f);
        float ex = (wv > 0.f) ? __expf(wv) : 0.f;
        ex = valid ? ex : 0.f;
        rs += ex;
        pk[4 + e] = f2bf(valid ? (ex + EPSC) : 0.f);
      }
      afrag[sub] = pk;
    }
    // write staged chunk to LDS
    #pragma unroll
    for (int p = 0; p < 4; ++p) {
      int z = t + 512 * p;
      *(bf16x8*)(sB + (z >> 3) * 144 + (z & 7) * 16) = st[p];
    }
    __syncthreads();
    #pragma unroll
    for (int sub = 0; sub < 2; ++sub) {
      #pragma unroll
      for (int n = 0; n < 16; ++n) {
        bf16x8 bb = *(const bf16x8*)(sB + (n * 16 + lr) * 144 + sub * 64 + lg * 16);
        acc[n] = __builtin_amdgcn_mfma_f32_16x16x32_bf16(afrag[sub], bb, acc[n], 0, 0, 0);
      }
    }
    __syncthreads();
  }

  // ---- row-sum reduce (across lg lanes) and scale accumulators ----
  rs += __shfl_xor(rs, 16, 64);
  rs += __shfl_xor(rs, 32, 64);
  const float scale = 1.0f / (rs + 257.0f * EPSC);   // lane holds scale for row lr
  float srow[4];
  #pragma unroll
  for (int r = 0; r < 4; ++r) srow[r] = __shfl(scale, lg * 4 + r, 64);
  #pragma unroll
  for (int n = 0; n < 16; ++n) {
    acc[n][0] *= srow[0]; acc[n][1] *= srow[1];
    acc[n][2] *= srow[2]; acc[n][3] *= srow[3];
  }

  // ---- second half: bf16(H) @ W2 (k = 256..511), 4 chunks of K=64 ----
  for (int c = 0; c < 4; ++c) {
    const int kk = c * 64;
    // stage sA: H rows fp32 -> bf16 (128 rows x 64 k)
    #pragma unroll
    for (int p = 0; p < 2; ++p) {
      int z = t + 512 * p;
      int row = z >> 3, s = z & 7;
      const float* src = H + ((size_t)b * 256 + i0 + row) * 256 + kk + s * 8;
      f32x4 x0 = *(const f32x4*)src;
      f32x4 x1 = *(const f32x4*)(src + 4);
      bf16x8 pk;
      pk[0] = f2bf(x0[0]); pk[1] = f2bf(x0[1]); pk[2] = f2bf(x0[2]); pk[3] = f2bf(x0[3]);
      pk[4] = f2bf(x1[0]); pk[5] = f2bf(x1[1]); pk[6] = f2bf(x1[2]); pk[7] = f2bf(x1[3]);
      *(bf16x8*)(sA + row * 144 + s * 16) = pk;
    }
    // stage sB: Wbf second-half chunk (256 d x 64 k)
    #pragma unroll
    for (int p = 0; p < 4; ++p) {
      int z = t + 512 * p;
      bf16x8 v = *(const bf16x8*)(Wbf + (size_t)(z >> 3) * 512 + 256 + kk + (z & 7) * 8);
      *(bf16x8*)(sB + (z >> 3) * 144 + (z & 7) * 16) = v;
    }
    __syncthreads();
    #pragma unroll
    for (int sub = 0; sub < 2; ++sub) {
      bf16x8 av = *(const bf16x8*)(sA + (wid * 16 + lr) * 144 + sub * 64 + lg * 16);
      #pragma unroll
      for (int n = 0; n < 16; ++n) {
        bf16x8 bb = *(const bf16x8*)(sB + (n * 16 + lr) * 144 + sub * 64 + lg * 16);
        acc[n] = __builtin_amdgcn_mfma_f32_16x16x32_bf16(av, bb, acc[n], 0, 0, 0);
      }
    }
    __syncthreads();
  }

  // ---- epilogue: + bias, store ----
  #pragma unroll
  for (int n = 0; n < 16; ++n) {
    int d = n * 16 + lr;
    float bs = sBias[d];
    #pragma unroll
    for (int r = 0; r < 4; ++r) {
      int row = wid * 16 + lg * 4 + r;
      out[((size_t)b * 256 + i0 + row) * 256 + d] = acc[n][r] + bs;
    }
  }
}

extern "C" void kernel_launch(void* const* d_in, const int* in_sizes, int n_in,
                              void* d_out, int out_size, void* d_ws, size_t ws_size,
                              hipStream_t stream) {
  const float* hidden  = (const float*)d_in[0];
  const float* dist    = (const float*)d_in[1];
  const float* bear    = (const float*)d_in[2];
  const float* head    = (const float*)d_in[3];
  const float* seqmask = (const float*)d_in[4];
  const float* domain  = (const float*)d_in[5];
  const float* W       = (const float*)d_in[6];
  const float* bias    = (const float*)d_in[7];
  float* out = (float*)d_out;

  char* ws = (char*)d_ws;
  short* Wbf = (short*)ws;                                   // 512 KB
  short* P1T = (short*)(ws + (1u << 20));                    // 32 MB

  k0_pack<<<128, 256, 0, stream>>>(W, Wbf);
  k1_proj<<<1024, 512, 46080, stream>>>(hidden, Wbf, P1T);
  k2_fused<<<512, 512, 78080, stream>>>(dist, bear, head, seqmask, domain,
                                        P1T, Wbf, hidden, bias, out);
}